// Round 7
// baseline (291.708 us; speedup 1.0000x reference)
//
#include <hip/hip_runtime.h>
#include <hip/hip_bf16.h>
#include <cstdint>

typedef unsigned short u16;
typedef __attribute__((ext_vector_type(8))) __bf16 bf16x8;
typedef __attribute__((ext_vector_type(4))) float f32x4;
typedef __attribute__((ext_vector_type(4))) short s16x4;
typedef __attribute__((ext_vector_type(4))) unsigned u32x4;

#define VSTR 4160  // padded Vt row stride (breaks 8KB power-of-2 aliasing)

__device__ __forceinline__ u16 f2bf(float f) {
  union { float f; unsigned u; } v; v.f = f;
  unsigned r = (v.u + 0x7FFFu + ((v.u >> 16) & 1u)) >> 16;
  return (u16)r;
}

__device__ __forceinline__ void gll16(const u16* gp, u16* lp) {
  auto g1 = reinterpret_cast<const __attribute__((address_space(1))) void*>(
      reinterpret_cast<uintptr_t>(gp));
  auto l3 = reinterpret_cast<__attribute__((address_space(3))) void*>(
      reinterpret_cast<uintptr_t>(lp));
  __builtin_amdgcn_global_load_lds(g1, l3, 16, 0, 0);
}

// ---------------------------------------------------------------------------
// Mask f32 [8][512][4096] (binary 0.0/1.0) -> bitmask, 1 bit/key.
// Thread t covers 16 consecutive keys of row t/256; emits one u16.
// ---------------------------------------------------------------------------
__global__ __launch_bounds__(256) void mask_bits(const float* __restrict__ mask,
                                                 u16* __restrict__ mb) {
  const int t = blockIdx.x * 256 + threadIdx.x;
  const float* src = mask + (size_t)t * 16;
  unsigned b = 0;
#pragma unroll
  for (int j = 0; j < 4; ++j) {
    const f32x4 v = *(const f32x4*)(src + 4 * j);
#pragma unroll
    for (int k = 0; k < 4; ++k) b |= (v[k] != 0.f ? 1u : 0u) << (4 * j + k);
  }
  mb[t] = (u16)b;
}

// ---------------------------------------------------------------------------
// Fused input LayerNorms: rows 0..4095 = original (dn, ot), 4096.. = resampled.
// ---------------------------------------------------------------------------
__global__ __launch_bounds__(128) void ln_all(
    const float* __restrict__ orig, const float* __restrict__ resam,
    const float* __restrict__ dn_s, const float* __restrict__ dn_o, u16* __restrict__ dinb,
    const float* __restrict__ ot_s, const float* __restrict__ ot_o, u16* __restrict__ otin,
    const float* __restrict__ qn_s, const float* __restrict__ qn_o, u16* __restrict__ qin) {
  const int row = blockIdx.x;
  const int t = threadIdx.x;
  const bool isOrig = row < 4096;
  const float* xr = isOrig ? orig + (size_t)row * 384 : resam + (size_t)(row - 4096) * 384;
  float v0 = xr[t], v1 = xr[t + 128], v2 = xr[t + 256];
  float sum = v0 + v1 + v2;
  float sq = v0 * v0 + v1 * v1 + v2 * v2;
#pragma unroll
  for (int off = 32; off > 0; off >>= 1) {
    sum += __shfl_xor(sum, off);
    sq += __shfl_xor(sq, off);
  }
  __shared__ float red[4];
  if ((t & 63) == 0) { red[(t >> 6) * 2] = sum; red[(t >> 6) * 2 + 1] = sq; }
  __syncthreads();
  sum = red[0] + red[2];
  sq = red[1] + red[3];
  const float mu = sum * (1.f / 384.f);
  const float rstd = rsqrtf(sq * (1.f / 384.f) - mu * mu + 1e-5f);
#pragma unroll
  for (int j = 0; j < 3; ++j) {
    const int cc = t + 128 * j;
    const float xv = (j == 0 ? v0 : (j == 1 ? v1 : v2));
    const float xn = (xv - mu) * rstd;
    if (isOrig) {
      dinb[(size_t)row * 384 + cc] = f2bf(dn_s[cc] * xn + dn_o[cc]);
      otin[(size_t)row * 384 + cc] = f2bf(ot_s[cc] * xn + ot_o[cc]);
    } else {
      qin[(size_t)(row - 4096) * 384 + cc] = f2bf(qn_s[cc] * xn + qn_o[cc]);
    }
  }
}

// Standalone LN (rt path, after P3).
__global__ __launch_bounds__(128) void ln_kernel(
    const float* __restrict__ x,
    const float* __restrict__ s1, const float* __restrict__ o1, u16* __restrict__ y1) {
  const int row = blockIdx.x;
  const int t = threadIdx.x;
  const float* xr = x + (size_t)row * 384;
  float v0 = xr[t], v1 = xr[t + 128], v2 = xr[t + 256];
  float sum = v0 + v1 + v2;
  float sq = v0 * v0 + v1 * v1 + v2 * v2;
#pragma unroll
  for (int off = 32; off > 0; off >>= 1) {
    sum += __shfl_xor(sum, off);
    sq += __shfl_xor(sq, off);
  }
  __shared__ float red[4];
  if ((t & 63) == 0) { red[(t >> 6) * 2] = sum; red[(t >> 6) * 2 + 1] = sq; }
  __syncthreads();
  sum = red[0] + red[2];
  sq = red[1] + red[3];
  const float mu = sum * (1.f / 384.f);
  const float rstd = rsqrtf(sq * (1.f / 384.f) - mu * mu + 1e-5f);
#pragma unroll
  for (int j = 0; j < 3; ++j) {
    const int cc = t + 128 * j;
    const float xv = (j == 0 ? v0 : (j == 1 ? v1 : v2));
    y1[(size_t)row * 384 + cc] = f2bf(s1[cc] * ((xv - mu) * rstd) + o1[cc]);
  }
}

// ---------------------------------------------------------------------------
// Batched f32 [K][N] -> bf16 [N][K] transposes (9 weight matrices, 1 launch).
// ---------------------------------------------------------------------------
struct TBatch {
  const float* in[9];
  u16* out[9];
  int K[9], N[9];
  float scale[9];
  int boff[10];
};

__global__ __launch_bounds__(256) void transpose_all(TBatch tb) {
  __shared__ float tile[32][33];
  const int bid = blockIdx.x;
  int j = 0;
  while (j < 8 && bid >= tb.boff[j + 1]) ++j;
  const int lb = bid - tb.boff[j];
  const int NB = tb.N[j] >> 5;
  const int bx = lb % NB, by = lb / NB;
  const float* in = tb.in[j];
  u16* out = tb.out[j];
  const int K = tb.K[j], N = tb.N[j];
  const float scale = tb.scale[j];
  const int tx = threadIdx.x, ty = threadIdx.y;
  const int nb = bx * 32, kb = by * 32;
#pragma unroll
  for (int i = 0; i < 4; ++i)
    tile[ty + 8 * i][tx] = in[(size_t)(kb + ty + 8 * i) * N + nb + tx];
  __syncthreads();
#pragma unroll
  for (int i = 0; i < 4; ++i)
    out[(size_t)(nb + ty + 8 * i) * K + kb + tx] = f2bf(tile[tx][ty + 8 * i] * scale);
}

// ---------------------------------------------------------------------------
// GEMM: C[M][N] = A[M][K] (bf16 row-major, ld=Kld) * Bt[N][K]^T. BK=64.
// Double-buffered global_load_lds staging, XOR-swizzled LDS, 4 waves 2x2.
// EPI: 0 bf16 relu(acc+bias); 1 f32 acc+bias+residual;
//      2 P1 (n<384 -> Kh[h][m][64] padded; else Vt[(n-384)][m], stride VSTR);
//      3 P2 (n<384 -> Qb[h][m][64] padded; else gate f32 sigmoid(acc+bias2));
//      4 split-K partial: outf[z*M*N + m*N+n] = acc
// ---------------------------------------------------------------------------
struct GArgs {
  const u16* A; const u16* Bt;
  int M, N, K, Kld;
  const float* bias; const float* bias2; const float* residual;
  float* outf; u16* outb; u16* outb2;
};

template <int BM, int BN, int EPI>
__global__ __launch_bounds__(256, (BM == 128 ? 2 : 4)) void gemm_bt(GArgs g) {
  constexpr int MT = BM / 32, NT = BN / 32;
  const int tid = threadIdx.x;
  const int w = tid >> 6;
  const int lane = tid & 63;
  const int gq = lane >> 4, c = lane & 15;
  const int brow = blockIdx.y * BM, bcol = blockIdx.x * BN;
  const int wm = (w >> 1) * (BM / 2), wn = (w & 1) * (BN / 2);
  __shared__ u16 As[2][BM][64];
  __shared__ u16 Bs[2][BN][64];
  const int K = g.K;
  const int Kld = g.Kld;
  const size_t koff = (size_t)blockIdx.z * K;

  f32x4 acc[MT][NT];
#pragma unroll
  for (int mt = 0; mt < MT; ++mt)
#pragma unroll
    for (int nt = 0; nt < NT; ++nt)
#pragma unroll
      for (int r = 0; r < 4; ++r) acc[mt][nt][r] = 0.f;

  const int srow = lane >> 3;
  const int schunk = (lane & 7) ^ srow;
  const u16* aSrc = g.A + (size_t)(brow + w * (BM / 4) + srow) * Kld + koff + schunk * 8;
  const u16* bSrc = g.Bt + (size_t)(bcol + w * (BN / 4) + srow) * Kld + koff + schunk * 8;

  auto STAGE = [&](int buf, int k0) {
#pragma unroll
    for (int i = 0; i < BM / 32; ++i)
      gll16(aSrc + (size_t)(8 * i) * Kld + k0, &As[buf][w * (BM / 4) + i * 8][0]);
#pragma unroll
    for (int i = 0; i < BN / 32; ++i)
      gll16(bSrc + (size_t)(8 * i) * Kld + k0, &Bs[buf][w * (BN / 4) + i * 8][0]);
  };

  auto COMPUTE = [&](int buf) {
#pragma unroll
    for (int ks = 0; ks < 2; ++ks) {
      bf16x8 af[MT], bfv[NT];
#pragma unroll
      for (int mt = 0; mt < MT; ++mt) {
        const int row = wm + mt * 16 + c;
        const int ch = ((ks << 2) | gq) ^ (row & 7);
        af[mt] = *(const bf16x8*)&As[buf][row][ch * 8];
      }
#pragma unroll
      for (int nt = 0; nt < NT; ++nt) {
        const int row = wn + nt * 16 + c;
        const int ch = ((ks << 2) | gq) ^ (row & 7);
        bfv[nt] = *(const bf16x8*)&Bs[buf][row][ch * 8];
      }
#pragma unroll
      for (int mt = 0; mt < MT; ++mt)
#pragma unroll
        for (int nt = 0; nt < NT; ++nt)
          acc[mt][nt] =
              __builtin_amdgcn_mfma_f32_16x16x32_bf16(af[mt], bfv[nt], acc[mt][nt], 0, 0, 0);
    }
  };

  const int NTILES = K >> 6;
  STAGE(0, 0);
  __syncthreads();
  int cur = 0;
  for (int t = 0; t < NTILES; ++t) {
    if (t + 1 < NTILES) STAGE(cur ^ 1, (t + 1) << 6);
    COMPUTE(cur);
    __syncthreads();
    cur ^= 1;
  }

  const int N = g.N;
#pragma unroll
  for (int mt = 0; mt < MT; ++mt) {
#pragma unroll
    for (int nt = 0; nt < NT; ++nt) {
      const int n = bcol + wn + nt * 16 + c;
#pragma unroll
      for (int r = 0; r < 4; ++r) {
        const int m = brow + wm + mt * 16 + 4 * gq + r;
        const float v = acc[mt][nt][r];
        if (EPI == 0) {
          g.outb[(size_t)m * N + n] = f2bf(fmaxf(v + g.bias[n], 0.f));
        } else if (EPI == 1) {
          g.outf[(size_t)m * N + n] = v + g.bias[n] + g.residual[(size_t)m * N + n];
        } else if (EPI == 2) {
          if (n < 384)
            g.outb[(size_t)(n / 48) * 4096 * 64 + (size_t)m * 64 + (n % 48)] = f2bf(v);
          else
            g.outb2[(size_t)(n - 384) * VSTR + m] = f2bf(v);
        } else if (EPI == 3) {
          if (n < 384)
            g.outb[(size_t)(n / 48) * 512 * 64 + (size_t)m * 64 + (n % 48)] = f2bf(v);
          else {
            const float sg = v + g.bias2[n - 384];
            g.outf[(size_t)m * 384 + (n - 384)] = 1.f / (1.f + __expf(-sg));
          }
        } else {
          g.outf[(size_t)blockIdx.z * g.M * N + (size_t)m * N + n] = v;
        }
      }
    }
  }
}

// ---------------------------------------------------------------------------
// Attention, bitmask + all-loads-upfront. p = bit ? exp(s) : 0 (exact).
// Grid (32 qt, 8 h, 8 z). Block 256 = 4 waves; wave w owns keys
// [z*512 + w*128, +128) for 16 q rows. 43 independent VMEM issued before any
// compute (sched_barrier pins the boundary); launch_bounds(256,2) gives the
// register budget (~256) so the compiler keeps them live instead of sinking.
// Kh bf16 [8][4096][64] (d padded). Qb bf16 [8][512][64]. Vt bf16 [384][VSTR].
// mbits [8*512 rows][512B]: bit k of row = mask[h][q][k].
// ---------------------------------------------------------------------------
__global__ __launch_bounds__(256, 2) void attn_kernel(
    const u16* __restrict__ Kh, const u16* __restrict__ Qb, const u16* __restrict__ Vt,
    const unsigned char* __restrict__ mbits, float* __restrict__ partO,
    float* __restrict__ partL) {
  const int tid = threadIdx.x;
  const int w = tid >> 6;
  const int lane = tid & 63;
  const int gq = lane >> 4, c = lane & 15;
  const int qt = blockIdx.x, h = blockIdx.y, z = blockIdx.z;
  const int tb = qt * 16;
  const int kb = z * 512 + w * 128;

  // ---- issue ALL loads up front ----
  const u16* qrow = Qb + ((size_t)h * 512 + tb + c) * 64;
  const bf16x8 qf0 = *(const bf16x8*)(qrow + 8 * gq);
  const bf16x8 qf1 = *(const bf16x8*)(qrow + 32 + 8 * gq);

  const u16* kbase = Kh + (size_t)h * 4096 * 64 + (size_t)(kb + c) * 64 + 8 * gq;
  bf16x8 kf[16];
#pragma unroll
  for (int it = 0; it < 4; ++it) {
    const u16* kr = kbase + it * 32 * 64;
    kf[4 * it + 0] = *(const bf16x8*)(kr);
    kf[4 * it + 1] = *(const bf16x8*)(kr + 32);
    kf[4 * it + 2] = *(const bf16x8*)(kr + 16 * 64);
    kf[4 * it + 3] = *(const bf16x8*)(kr + 16 * 64 + 32);
  }

  s16x4 vv[4][3][2];
#pragma unroll
  for (int nt = 0; nt < 3; ++nt) {
    const u16* vc = Vt + ((size_t)h * 48 + nt * 16 + c) * VSTR + kb + 4 * gq;
#pragma unroll
    for (int it = 0; it < 4; ++it) {
      vv[it][nt][0] = *(const s16x4*)(vc + it * 32);
      vv[it][nt][1] = *(const s16x4*)(vc + it * 32 + 16);
    }
  }

  const u32x4 mb =
      *(const u32x4*)(mbits + ((size_t)h * 512 + tb + c) * 512 + (kb >> 3));

  __builtin_amdgcn_sched_barrier(0);

  f32x4 O0, O1, O2;
#pragma unroll
  for (int r = 0; r < 4; ++r) { O0[r] = 0.f; O1[r] = 0.f; O2[r] = 0.f; }
  float psum = 0.f;

#pragma unroll
  for (int it = 0; it < 4; ++it) {
    f32x4 z4;
#pragma unroll
    for (int r = 0; r < 4; ++r) z4[r] = 0.f;
    f32x4 s0 = __builtin_amdgcn_mfma_f32_16x16x32_bf16(kf[4 * it + 0], qf0, z4, 0, 0, 0);
    s0 = __builtin_amdgcn_mfma_f32_16x16x32_bf16(kf[4 * it + 1], qf1, s0, 0, 0, 0);
    f32x4 s1 = __builtin_amdgcn_mfma_f32_16x16x32_bf16(kf[4 * it + 2], qf0, z4, 0, 0, 0);
    s1 = __builtin_amdgcn_mfma_f32_16x16x32_bf16(kf[4 * it + 3], qf1, s1, 0, 0, 0);

    const unsigned wd0 = mb[it] >> (4 * gq);
    const unsigned wd1 = mb[it] >> (16 + 4 * gq);
    float p0[4], p1[4];
#pragma unroll
    for (int r = 0; r < 4; ++r) {
      p0[r] = ((wd0 >> r) & 1u) ? __expf(s0[r]) : 0.f;
      p1[r] = ((wd1 >> r) & 1u) ? __expf(s1[r]) : 0.f;
      psum += p0[r] + p1[r];
    }
    s16x4 pa0, pa1;
    ((unsigned*)&pa0)[0] = __builtin_amdgcn_perm(__builtin_bit_cast(unsigned, p0[1]),
                                                 __builtin_bit_cast(unsigned, p0[0]), 0x07060302u);
    ((unsigned*)&pa0)[1] = __builtin_amdgcn_perm(__builtin_bit_cast(unsigned, p0[3]),
                                                 __builtin_bit_cast(unsigned, p0[2]), 0x07060302u);
    ((unsigned*)&pa1)[0] = __builtin_amdgcn_perm(__builtin_bit_cast(unsigned, p1[1]),
                                                 __builtin_bit_cast(unsigned, p1[0]), 0x07060302u);
    ((unsigned*)&pa1)[1] = __builtin_amdgcn_perm(__builtin_bit_cast(unsigned, p1[3]),
                                                 __builtin_bit_cast(unsigned, p1[2]), 0x07060302u);
    O0 = __builtin_amdgcn_mfma_f32_16x16x16bf16_1k(pa0, vv[it][0][0], O0, 0, 0, 0);
    O0 = __builtin_amdgcn_mfma_f32_16x16x16bf16_1k(pa1, vv[it][0][1], O0, 0, 0, 0);
    O1 = __builtin_amdgcn_mfma_f32_16x16x16bf16_1k(pa0, vv[it][1][0], O1, 0, 0, 0);
    O1 = __builtin_amdgcn_mfma_f32_16x16x16bf16_1k(pa1, vv[it][1][1], O1, 0, 0, 0);
    O2 = __builtin_amdgcn_mfma_f32_16x16x16bf16_1k(pa0, vv[it][2][0], O2, 0, 0, 0);
    O2 = __builtin_amdgcn_mfma_f32_16x16x16bf16_1k(pa1, vv[it][2][1], O2, 0, 0, 0);
  }

  psum += __shfl_xor(psum, 16);
  psum += __shfl_xor(psum, 32);

  __shared__ float oS[4][16][48];
  __shared__ float lS[4][16];
  if (gq == 0) lS[w][c] = psum;
#pragma unroll
  for (int r = 0; r < 4; ++r) {
    oS[w][4 * gq + r][c] = O0[r];
    oS[w][4 * gq + r][16 + c] = O1[r];
    oS[w][4 * gq + r][32 + c] = O2[r];
  }
  __syncthreads();

  float* pO = partO + (((size_t)z * 32 + qt) * 8 + h) * 768;
  for (int idx = tid; idx < 768; idx += 256) {
    const int q = idx / 48, d = idx % 48;
    float v = 0.f;
#pragma unroll
    for (int ww = 0; ww < 4; ++ww) v += oS[ww][q][d];
    pO[idx] = v;
  }
  if (tid < 16) {
    float L = 0.f;
#pragma unroll
    for (int ww = 0; ww < 4; ++ww) L += lS[ww][tid];
    partL[(((size_t)z * 32 + qt) * 8 + h) * 16 + tid] = L;
  }
}

// Combine 8 key-split partials, apply 1/l and gate.
__global__ __launch_bounds__(256) void attn_merge(
    const float* __restrict__ partO, const float* __restrict__ partL,
    const float* __restrict__ gate, u16* __restrict__ attng) {
  const int qt = blockIdx.x, h = blockIdx.y;
  for (int idx = threadIdx.x; idx < 768; idx += 256) {
    const int q = idx / 48, d = idx % 48;
    float O = 0.f, L = 0.f;
#pragma unroll
    for (int z = 0; z < 8; ++z) {
      O += partO[(((size_t)z * 32 + qt) * 8 + h) * 768 + idx];
      L += partL[(((size_t)z * 32 + qt) * 8 + h) * 16 + q];
    }
    const size_t off = (size_t)(qt * 16 + q) * 384 + h * 48 + d;
    attng[off] = f2bf(O / L * gate[off]);
  }
}

// Merge T1 split-K partials + bias + residual -> out_res.
__global__ __launch_bounds__(256) void merge_res(
    const float* __restrict__ pT1, const float* __restrict__ res2,
    const float* __restrict__ rtb2, float* __restrict__ out_res) {
  const int i = blockIdx.x * 256 + threadIdx.x;  // 512*384/4 = 49152 threads
  const int n0 = (i * 4) % 384;
  f32x4 v = *(const f32x4*)(res2 + (size_t)i * 4);
#pragma unroll
  for (int z = 0; z < 4; ++z) {
    const f32x4 pz = *(const f32x4*)(pT1 + (size_t)z * 512 * 384 + (size_t)i * 4);
#pragma unroll
    for (int r = 0; r < 4; ++r) v[r] += pz[r];
  }
  const f32x4 b = *(const f32x4*)(rtb2 + n0);
#pragma unroll
  for (int r = 0; r < 4; ++r) v[r] += b[r];
  *(f32x4*)(out_res + (size_t)i * 4) = v;
}

// ---------------------------------------------------------------------------
extern "C" void kernel_launch(void* const* d_in, const int* in_sizes, int n_in,
                              void* d_out, int out_size, void* d_ws, size_t ws_size,
                              hipStream_t stream) {
  (void)in_sizes; (void)n_in; (void)out_size; (void)ws_size;
  const float* original = (const float*)d_in[0];
  const float* resampled = (const float*)d_in[1];
  const float* amask = (const float*)d_in[2];
  const float* qn_s = (const float*)d_in[5];
  const float* qn_o = (const float*)d_in[6];
  const float* dn_s = (const float*)d_in[7];
  const float* dn_o = (const float*)d_in[8];
  const float* w_q = (const float*)d_in[9];
  const float* w_k = (const float*)d_in[10];
  const float* w_v = (const float*)d_in[11];
  const float* w_g = (const float*)d_in[12];
  const float* b_g = (const float*)d_in[13];
  const float* w_o = (const float*)d_in[14];
  const float* b_o = (const float*)d_in[15];
  const float* rt_s = (const float*)d_in[16];
  const float* rt_o = (const float*)d_in[17];
  const float* rtw1 = (const float*)d_in[18];
  const float* rtb1 = (const float*)d_in[19];
  const float* rtw2 = (const float*)d_in[20];
  const float* rtb2 = (const float*)d_in[21];
  const float* ot_s = (const float*)d_in[22];
  const float* ot_o = (const float*)d_in[23];
  const float* otw1 = (const float*)d_in[24];
  const float* otb1 = (const float*)d_in[25];
  const float* otw2 = (const float*)d_in[26];
  const float* otb2 = (const float*)d_in[27];

  float* out_res = (float*)d_out;
  float* out_orig = out_res + 512 * 384;

  char* p = (char*)d_ws;
  auto alloc = [&](size_t n) {
    void* r = (void*)p;
    p += (n + 255) & ~(size_t)255;
    return r;
  };
  u16* Kh = (u16*)alloc((size_t)8 * 4096 * 64 * 2);  // padded K (memset 0)
  u16* Qb = (u16*)alloc((size_t)8 * 512 * 64 * 2);   // padded Q (memset 0, adjacent)
  u16* dinb = (u16*)alloc(4096 * 384 * 2);
  u16* otin = (u16*)alloc(4096 * 384 * 2);
  u16* qin = (u16*)alloc(512 * 384 * 2);
  u16* Vt = (u16*)alloc((size_t)384 * VSTR * 2);
  float* gateb = (float*)alloc(512 * 384 * 4);
  u16* attng = (u16*)alloc(512 * 384 * 2);
  float* res2 = (float*)alloc(512 * 384 * 4);
  u16* tin = (u16*)alloc(512 * 384 * 2);
  u16* H1 = (u16*)alloc(512 * 1536 * 2);
  u16* H2 = (u16*)alloc((size_t)4096 * 1536 * 2);
  float* partT1 = (float*)alloc((size_t)4 * 512 * 384 * 4);
  float* partO = (float*)alloc((size_t)8 * 32 * 8 * 768 * 4);
  float* partL = (float*)alloc((size_t)8 * 32 * 8 * 16 * 4);
  u16* mbitsB = (u16*)alloc((size_t)8 * 512 * 512);  // 2MB bitmask
  u16* BtKV = (u16*)alloc(768 * 384 * 2);
  u16* BtQG = (u16*)alloc(768 * 384 * 2);
  u16* OwT = (u16*)alloc(384 * 384 * 2);
  u16* Rt1T = (u16*)alloc(1536 * 384 * 2);
  u16* Rt2T = (u16*)alloc(384 * 1536 * 2);
  u16* Ot1T = (u16*)alloc(1536 * 384 * 2);
  u16* Ot2T = (u16*)alloc(384 * 1536 * 2);

  // zero the d-padding of Kh and Qb (adjacent allocations)
  hipMemsetAsync(Kh, 0, (size_t)8 * 4096 * 64 * 2 + (size_t)8 * 512 * 64 * 2, stream);

  mask_bits<<<4096, 256, 0, stream>>>(amask, mbitsB);

  {
    TBatch tb{};
    const float qscale = 0.14433756729740643f;  // 48^-0.5
    const float* ins[9] = {w_q, w_g, w_k, w_v, w_o, rtw1, rtw2, otw1, otw2};
    u16* outs[9] = {BtQG, BtQG + 384 * 384, BtKV, BtKV + 384 * 384, OwT,
                    Rt1T, Rt2T, Ot1T, Ot2T};
    const int Ks[9] = {384, 384, 384, 384, 384, 384, 1536, 384, 1536};
    const int Ns[9] = {384, 384, 384, 384, 384, 1536, 384, 1536, 384};
    int off = 0;
    for (int j = 0; j < 9; ++j) {
      tb.in[j] = ins[j]; tb.out[j] = outs[j];
      tb.K[j] = Ks[j]; tb.N[j] = Ns[j];
      tb.scale[j] = (j == 0) ? qscale : 1.f;
      tb.boff[j] = off;
      off += (Ns[j] >> 5) * (Ks[j] >> 5);
    }
    tb.boff[9] = off;
    transpose_all<<<off, dim3(32, 8), 0, stream>>>(tb);
  }

  ln_all<<<4608, 128, 0, stream>>>(original, resampled, dn_s, dn_o, dinb,
                                   ot_s, ot_o, otin, qn_s, qn_o, qin);

  {  // P1: K/V projections
    GArgs a{};
    a.A = dinb; a.Bt = BtKV; a.M = 4096; a.N = 768; a.K = 384; a.Kld = 384;
    a.outb = Kh; a.outb2 = Vt;
    gemm_bt<128, 128, 2><<<dim3(6, 32), 256, 0, stream>>>(a);
  }
  {  // P2: Q/gate projections
    GArgs a{};
    a.A = qin; a.Bt = BtQG; a.M = 512; a.N = 768; a.K = 384; a.Kld = 384;
    a.outb = Qb; a.outf = gateb; a.bias2 = b_g;
    gemm_bt<64, 64, 3><<<dim3(12, 8), 256, 0, stream>>>(a);
  }

  attn_kernel<<<dim3(32, 8, 8), 256, 0, stream>>>(
      Kh, Qb, Vt, (const unsigned char*)mbitsB, partO, partL);
  attn_merge<<<dim3(32, 8), 256, 0, stream>>>(partO, partL, gateb, attng);

  {  // P3: output projection + residual -> res2
    GArgs a{};
    a.A = attng; a.Bt = OwT; a.M = 512; a.N = 384; a.K = 384; a.Kld = 384;
    a.bias = b_o; a.residual = resampled; a.outf = res2;
    gemm_bt<64, 64, 1><<<dim3(6, 8), 256, 0, stream>>>(a);
  }
  ln_kernel<<<512, 128, 0, stream>>>(res2, rt_s, rt_o, tin);
  {  // T1a
    GArgs a{};
    a.A = tin; a.Bt = Rt1T; a.M = 512; a.N = 1536; a.K = 384; a.Kld = 384;
    a.bias = rtb1; a.outb = H1;
    gemm_bt<64, 64, 0><<<dim3(24, 8), 256, 0, stream>>>(a);
  }
  {  // T1b split-K=4 -> partT1 (grid would otherwise be 48 blocks)
    GArgs a{};
    a.A = H1; a.Bt = Rt2T; a.M = 512; a.N = 384; a.K = 384; a.Kld = 1536;
    a.outf = partT1;
    gemm_bt<64, 64, 4><<<dim3(6, 8, 4), 256, 0, stream>>>(a);
  }
  {  // T2a
    GArgs a{};
    a.A = otin; a.Bt = Ot1T; a.M = 4096; a.N = 1536; a.K = 384; a.Kld = 384;
    a.bias = otb1; a.outb = H2;
    gemm_bt<128, 128, 0><<<dim3(12, 32), 256, 0, stream>>>(a);
  }
  {  // T2b direct (384 blocks already fills the GPU; split-K was pure overhead)
    GArgs a{};
    a.A = H2; a.Bt = Ot2T; a.M = 4096; a.N = 384; a.K = 1536; a.Kld = 1536;
    a.bias = otb2; a.residual = original; a.outf = out_orig;
    gemm_bt<64, 64, 1><<<dim3(6, 64), 256, 0, stream>>>(a);
  }
  merge_res<<<192, 256, 0, stream>>>(partT1, res2, rtb2, out_res);
}

// Round 8
// 261.315 us; speedup vs baseline: 1.1163x; 1.1163x over previous
//
#include <hip/hip_runtime.h>
#include <hip/hip_bf16.h>
#include <cstdint>

typedef unsigned short u16;
typedef __attribute__((ext_vector_type(8))) __bf16 bf16x8;
typedef __attribute__((ext_vector_type(4))) float f32x4;
typedef __attribute__((ext_vector_type(4))) short s16x4;
typedef __attribute__((ext_vector_type(4))) unsigned u32x4;

#define VSTR 4160  // padded Vt row stride

__device__ __forceinline__ u16 f2bf(float f) {
  union { float f; unsigned u; } v; v.f = f;
  unsigned r = (v.u + 0x7FFFu + ((v.u >> 16) & 1u)) >> 16;
  return (u16)r;
}

__device__ __forceinline__ void gll16(const u16* gp, u16* lp) {
  auto g1 = reinterpret_cast<const __attribute__((address_space(1))) void*>(
      reinterpret_cast<uintptr_t>(gp));
  auto l3 = reinterpret_cast<__attribute__((address_space(3))) void*>(
      reinterpret_cast<uintptr_t>(lp));
  __builtin_amdgcn_global_load_lds(g1, l3, 16, 0, 0);
}

// ---------------------------------------------------------------------------
// Mask f32 [8][512][4096] (binary) -> bitmask, 1 bit/key.
// ---------------------------------------------------------------------------
__global__ __launch_bounds__(256) void mask_bits(const float* __restrict__ mask,
                                                 u16* __restrict__ mb) {
  const int t = blockIdx.x * 256 + threadIdx.x;
  const float* src = mask + (size_t)t * 16;
  unsigned b = 0;
#pragma unroll
  for (int j = 0; j < 4; ++j) {
    const f32x4 v = *(const f32x4*)(src + 4 * j);
#pragma unroll
    for (int k = 0; k < 4; ++k) b |= (v[k] != 0.f ? 1u : 0u) << (4 * j + k);
  }
  mb[t] = (u16)b;
}

// ---------------------------------------------------------------------------
// Fused input LayerNorms.
// ---------------------------------------------------------------------------
__global__ __launch_bounds__(128) void ln_all(
    const float* __restrict__ orig, const float* __restrict__ resam,
    const float* __restrict__ dn_s, const float* __restrict__ dn_o, u16* __restrict__ dinb,
    const float* __restrict__ ot_s, const float* __restrict__ ot_o, u16* __restrict__ otin,
    const float* __restrict__ qn_s, const float* __restrict__ qn_o, u16* __restrict__ qin) {
  const int row = blockIdx.x;
  const int t = threadIdx.x;
  const bool isOrig = row < 4096;
  const float* xr = isOrig ? orig + (size_t)row * 384 : resam + (size_t)(row - 4096) * 384;
  float v0 = xr[t], v1 = xr[t + 128], v2 = xr[t + 256];
  float sum = v0 + v1 + v2;
  float sq = v0 * v0 + v1 * v1 + v2 * v2;
#pragma unroll
  for (int off = 32; off > 0; off >>= 1) {
    sum += __shfl_xor(sum, off);
    sq += __shfl_xor(sq, off);
  }
  __shared__ float red[4];
  if ((t & 63) == 0) { red[(t >> 6) * 2] = sum; red[(t >> 6) * 2 + 1] = sq; }
  __syncthreads();
  sum = red[0] + red[2];
  sq = red[1] + red[3];
  const float mu = sum * (1.f / 384.f);
  const float rstd = rsqrtf(sq * (1.f / 384.f) - mu * mu + 1e-5f);
#pragma unroll
  for (int j = 0; j < 3; ++j) {
    const int cc = t + 128 * j;
    const float xv = (j == 0 ? v0 : (j == 1 ? v1 : v2));
    const float xn = (xv - mu) * rstd;
    if (isOrig) {
      dinb[(size_t)row * 384 + cc] = f2bf(dn_s[cc] * xn + dn_o[cc]);
      otin[(size_t)row * 384 + cc] = f2bf(ot_s[cc] * xn + ot_o[cc]);
    } else {
      qin[(size_t)(row - 4096) * 384 + cc] = f2bf(qn_s[cc] * xn + qn_o[cc]);
    }
  }
}

__global__ __launch_bounds__(128) void ln_kernel(
    const float* __restrict__ x,
    const float* __restrict__ s1, const float* __restrict__ o1, u16* __restrict__ y1) {
  const int row = blockIdx.x;
  const int t = threadIdx.x;
  const float* xr = x + (size_t)row * 384;
  float v0 = xr[t], v1 = xr[t + 128], v2 = xr[t + 256];
  float sum = v0 + v1 + v2;
  float sq = v0 * v0 + v1 * v1 + v2 * v2;
#pragma unroll
  for (int off = 32; off > 0; off >>= 1) {
    sum += __shfl_xor(sum, off);
    sq += __shfl_xor(sq, off);
  }
  __shared__ float red[4];
  if ((t & 63) == 0) { red[(t >> 6) * 2] = sum; red[(t >> 6) * 2 + 1] = sq; }
  __syncthreads();
  sum = red[0] + red[2];
  sq = red[1] + red[3];
  const float mu = sum * (1.f / 384.f);
  const float rstd = rsqrtf(sq * (1.f / 384.f) - mu * mu + 1e-5f);
#pragma unroll
  for (int j = 0; j < 3; ++j) {
    const int cc = t + 128 * j;
    const float xv = (j == 0 ? v0 : (j == 1 ? v1 : v2));
    y1[(size_t)row * 384 + cc] = f2bf(s1[cc] * ((xv - mu) * rstd) + o1[cc]);
  }
}

// ---------------------------------------------------------------------------
// Batched weight transposes.
// ---------------------------------------------------------------------------
struct TBatch {
  const float* in[9];
  u16* out[9];
  int K[9], N[9];
  float scale[9];
  int boff[10];
};

__global__ __launch_bounds__(256) void transpose_all(TBatch tb) {
  __shared__ float tile[32][33];
  const int bid = blockIdx.x;
  int j = 0;
  while (j < 8 && bid >= tb.boff[j + 1]) ++j;
  const int lb = bid - tb.boff[j];
  const int NB = tb.N[j] >> 5;
  const int bx = lb % NB, by = lb / NB;
  const float* in = tb.in[j];
  u16* out = tb.out[j];
  const int K = tb.K[j], N = tb.N[j];
  const float scale = tb.scale[j];
  const int tx = threadIdx.x, ty = threadIdx.y;
  const int nb = bx * 32, kb = by * 32;
#pragma unroll
  for (int i = 0; i < 4; ++i)
    tile[ty + 8 * i][tx] = in[(size_t)(kb + ty + 8 * i) * N + nb + tx];
  __syncthreads();
#pragma unroll
  for (int i = 0; i < 4; ++i)
    out[(size_t)(nb + ty + 8 * i) * K + kb + tx] = f2bf(tile[tx][ty + 8 * i] * scale);
}

// ---------------------------------------------------------------------------
// GEMM (as before). EPI 0/1/2/3/4.
// ---------------------------------------------------------------------------
struct GArgs {
  const u16* A; const u16* Bt;
  int M, N, K, Kld;
  const float* bias; const float* bias2; const float* residual;
  float* outf; u16* outb; u16* outb2;
};

template <int BM, int BN, int EPI>
__global__ __launch_bounds__(256, (BM == 128 ? 2 : 4)) void gemm_bt(GArgs g) {
  constexpr int MT = BM / 32, NT = BN / 32;
  const int tid = threadIdx.x;
  const int w = tid >> 6;
  const int lane = tid & 63;
  const int gq = lane >> 4, c = lane & 15;
  const int brow = blockIdx.y * BM, bcol = blockIdx.x * BN;
  const int wm = (w >> 1) * (BM / 2), wn = (w & 1) * (BN / 2);
  __shared__ u16 As[2][BM][64];
  __shared__ u16 Bs[2][BN][64];
  const int K = g.K;
  const int Kld = g.Kld;
  const size_t koff = (size_t)blockIdx.z * K;

  f32x4 acc[MT][NT];
#pragma unroll
  for (int mt = 0; mt < MT; ++mt)
#pragma unroll
    for (int nt = 0; nt < NT; ++nt)
#pragma unroll
      for (int r = 0; r < 4; ++r) acc[mt][nt][r] = 0.f;

  const int srow = lane >> 3;
  const int schunk = (lane & 7) ^ srow;
  const u16* aSrc = g.A + (size_t)(brow + w * (BM / 4) + srow) * Kld + koff + schunk * 8;
  const u16* bSrc = g.Bt + (size_t)(bcol + w * (BN / 4) + srow) * Kld + koff + schunk * 8;

  auto STAGE = [&](int buf, int k0) {
#pragma unroll
    for (int i = 0; i < BM / 32; ++i)
      gll16(aSrc + (size_t)(8 * i) * Kld + k0, &As[buf][w * (BM / 4) + i * 8][0]);
#pragma unroll
    for (int i = 0; i < BN / 32; ++i)
      gll16(bSrc + (size_t)(8 * i) * Kld + k0, &Bs[buf][w * (BN / 4) + i * 8][0]);
  };

  auto COMPUTE = [&](int buf) {
#pragma unroll
    for (int ks = 0; ks < 2; ++ks) {
      bf16x8 af[MT], bfv[NT];
#pragma unroll
      for (int mt = 0; mt < MT; ++mt) {
        const int row = wm + mt * 16 + c;
        const int ch = ((ks << 2) | gq) ^ (row & 7);
        af[mt] = *(const bf16x8*)&As[buf][row][ch * 8];
      }
#pragma unroll
      for (int nt = 0; nt < NT; ++nt) {
        const int row = wn + nt * 16 + c;
        const int ch = ((ks << 2) | gq) ^ (row & 7);
        bfv[nt] = *(const bf16x8*)&Bs[buf][row][ch * 8];
      }
#pragma unroll
      for (int mt = 0; mt < MT; ++mt)
#pragma unroll
        for (int nt = 0; nt < NT; ++nt)
          acc[mt][nt] =
              __builtin_amdgcn_mfma_f32_16x16x32_bf16(af[mt], bfv[nt], acc[mt][nt], 0, 0, 0);
    }
  };

  const int NTILES = K >> 6;
  STAGE(0, 0);
  __syncthreads();
  int cur = 0;
  for (int t = 0; t < NTILES; ++t) {
    if (t + 1 < NTILES) STAGE(cur ^ 1, (t + 1) << 6);
    COMPUTE(cur);
    __syncthreads();
    cur ^= 1;
  }

  const int N = g.N;
#pragma unroll
  for (int mt = 0; mt < MT; ++mt) {
#pragma unroll
    for (int nt = 0; nt < NT; ++nt) {
      const int n = bcol + wn + nt * 16 + c;
#pragma unroll
      for (int r = 0; r < 4; ++r) {
        const int m = brow + wm + mt * 16 + 4 * gq + r;
        const float v = acc[mt][nt][r];
        if (EPI == 0) {
          g.outb[(size_t)m * N + n] = f2bf(fmaxf(v + g.bias[n], 0.f));
        } else if (EPI == 1) {
          g.outf[(size_t)m * N + n] = v + g.bias[n] + g.residual[(size_t)m * N + n];
        } else if (EPI == 2) {
          if (n < 384)
            g.outb[(size_t)(n / 48) * 4096 * 64 + (size_t)m * 64 + (n % 48)] = f2bf(v);
          else
            g.outb2[(size_t)(n - 384) * VSTR + m] = f2bf(v);
        } else if (EPI == 3) {
          if (n < 384)
            g.outb[(size_t)(n / 48) * 512 * 64 + (size_t)m * 64 + (n % 48)] = f2bf(v);
          else {
            const float sg = v + g.bias2[n - 384];
            g.outf[(size_t)m * 384 + (n - 384)] = 1.f / (1.f + __expf(-sg));
          }
        } else {
          g.outf[(size_t)blockIdx.z * g.M * N + (size_t)m * N + n] = v;
        }
      }
    }
  }
}

// ---------------------------------------------------------------------------
// Attention, GEMM-style LDS staging. Grid (8 qg, 8 h, 8 z) = 512 blocks,
// block = 4 waves; wave w owns q-rows qg*64 + w*16 ..+16; block covers keys
// [z*512, +512) in 4 chunks of 128, double-buffered in LDS. All 4 waves
// consume the same K/V tile (different q) -> staging amortized 4x, coalesced.
// K LDS [128][64] XOR-swizzled (16B chunk ^ row&7, via pre-swizzled source);
// V LDS [48][128] XOR-swizzled (16B chunk ^ row&15).
// p = bit ? exp(s) : 0 (exact for binary mask).
// ---------------------------------------------------------------------------
__global__ __launch_bounds__(256, 2) void attn_kernel(
    const u16* __restrict__ Kh, const u16* __restrict__ Qb, const u16* __restrict__ Vt,
    const unsigned char* __restrict__ mbits, float* __restrict__ partO,
    float* __restrict__ partL) {
  const int tid = threadIdx.x;
  const int w = tid >> 6;
  const int lane = tid & 63;
  const int gq = lane >> 4, c = lane & 15;
  const int qg = blockIdx.x, h = blockIdx.y, z = blockIdx.z;
  const int qt = qg * 4 + w;  // global 16-row q-tile owned by this wave
  const int kb = z * 512;     // block's key window

  __shared__ u16 Ks[2][128][64];  // 32KB
  __shared__ u16 Vs[2][48][128];  // 24KB

  // Q fragments (d padded to 64)
  const u16* qrow = Qb + ((size_t)h * 512 + qt * 16 + c) * 64;
  const bf16x8 qf0 = *(const bf16x8*)(qrow + 8 * gq);
  const bf16x8 qf1 = *(const bf16x8*)(qrow + 32 + 8 * gq);

  // mask words: 4 chunks x 128 bits for q-row (qt*16+c)
  const unsigned char* mrow = mbits + ((size_t)h * 512 + qt * 16 + c) * 512 + z * 64;
  u32x4 mbAll[4];
#pragma unroll
  for (int ch = 0; ch < 4; ++ch) mbAll[ch] = *(const u32x4*)(mrow + ch * 16);

  // staging lane mappings (pre-swizzled sources, linear LDS dests)
  const int krow8 = lane >> 3;                    // 0..7
  const int kch = (lane & 7) ^ krow8;             // K d-chunk (16B)
  const u16* kbase = Kh + (size_t)h * 4096 * 64;
  const int vrow4 = lane >> 4;                    // 0..3
  const int vk16 = lane & 15;                     // key 16B chunk

  auto STAGE = [&](int buf, int ch) {
    const int k0 = kb + ch * 128;
    // K: wave w stages rows w*32 .. w*32+31 (4 instrs x 8 rows)
#pragma unroll
    for (int j = 0; j < 4; ++j) {
      const int row = w * 32 + j * 8 + krow8;
      gll16(kbase + (size_t)(k0 + row) * 64 + kch * 8, &Ks[buf][w * 32 + j * 8][0]);
    }
    // V: wave w stages d-rows w*12 .. w*12+11 (3 instrs x 4 rows)
#pragma unroll
    for (int j = 0; j < 3; ++j) {
      const int d = w * 12 + j * 4 + vrow4;
      const int sk = vk16 ^ (d & 15);
      gll16(Vt + (size_t)(h * 48 + d) * VSTR + k0 + sk * 8, &Vs[buf][w * 12 + j * 4][0]);
    }
  };

  f32x4 O0, O1, O2;
#pragma unroll
  for (int r = 0; r < 4; ++r) { O0[r] = 0.f; O1[r] = 0.f; O2[r] = 0.f; }
  float psum = 0.f;
  f32x4 z4;
#pragma unroll
  for (int r = 0; r < 4; ++r) z4[r] = 0.f;

  STAGE(0, 0);
  __syncthreads();
  int cur = 0;
  for (int ch = 0; ch < 4; ++ch) {
    if (ch + 1 < 4) STAGE(cur ^ 1, ch + 1);
#pragma unroll
    for (int s = 0; s < 4; ++s) {  // 32-key subtiles within the 128-key chunk
      const int keyA = s * 32 + c;
      const int keyB = keyA + 16;
      const bf16x8 kA0 = *(const bf16x8*)&Ks[cur][keyA][(gq ^ (keyA & 7)) * 8];
      const bf16x8 kA1 = *(const bf16x8*)&Ks[cur][keyA][((4 + gq) ^ (keyA & 7)) * 8];
      const bf16x8 kB0 = *(const bf16x8*)&Ks[cur][keyB][(gq ^ (keyB & 7)) * 8];
      const bf16x8 kB1 = *(const bf16x8*)&Ks[cur][keyB][((4 + gq) ^ (keyB & 7)) * 8];

      f32x4 s0 = __builtin_amdgcn_mfma_f32_16x16x32_bf16(kA0, qf0, z4, 0, 0, 0);
      s0 = __builtin_amdgcn_mfma_f32_16x16x32_bf16(kA1, qf1, s0, 0, 0, 0);
      f32x4 s1 = __builtin_amdgcn_mfma_f32_16x16x32_bf16(kB0, qf0, z4, 0, 0, 0);
      s1 = __builtin_amdgcn_mfma_f32_16x16x32_bf16(kB1, qf1, s1, 0, 0, 0);

      const unsigned word = mbAll[ch][s];
      const unsigned wd0 = word >> (4 * gq);
      const unsigned wd1 = word >> (16 + 4 * gq);
      float p0[4], p1[4];
#pragma unroll
      for (int r = 0; r < 4; ++r) {
        p0[r] = ((wd0 >> r) & 1u) ? __expf(s0[r]) : 0.f;
        p1[r] = ((wd1 >> r) & 1u) ? __expf(s1[r]) : 0.f;
        psum += p0[r] + p1[r];
      }
      s16x4 pa0, pa1;
      ((unsigned*)&pa0)[0] = __builtin_amdgcn_perm(__builtin_bit_cast(unsigned, p0[1]),
                                                   __builtin_bit_cast(unsigned, p0[0]), 0x07060302u);
      ((unsigned*)&pa0)[1] = __builtin_amdgcn_perm(__builtin_bit_cast(unsigned, p0[3]),
                                                   __builtin_bit_cast(unsigned, p0[2]), 0x07060302u);
      ((unsigned*)&pa1)[0] = __builtin_amdgcn_perm(__builtin_bit_cast(unsigned, p1[1]),
                                                   __builtin_bit_cast(unsigned, p1[0]), 0x07060302u);
      ((unsigned*)&pa1)[1] = __builtin_amdgcn_perm(__builtin_bit_cast(unsigned, p1[3]),
                                                   __builtin_bit_cast(unsigned, p1[2]), 0x07060302u);

      // V fragments: key_local = s*32 + g2*16 + 4*gq (+r inside s16x4)
#pragma unroll
      for (int nt = 0; nt < 3; ++nt) {
        const int row = nt * 16 + c;
        const int klA = s * 32 + 4 * gq;
        const int klB = klA + 16;
        const s16x4 vfA = *(const s16x4*)&Vs[cur][row][(((klA >> 3) ^ c) << 3) + (gq & 1) * 4];
        const s16x4 vfB = *(const s16x4*)&Vs[cur][row][(((klB >> 3) ^ c) << 3) + (gq & 1) * 4];
        f32x4& O = (nt == 0 ? O0 : (nt == 1 ? O1 : O2));
        O = __builtin_amdgcn_mfma_f32_16x16x16bf16_1k(pa0, vfA, O, 0, 0, 0);
        O = __builtin_amdgcn_mfma_f32_16x16x16bf16_1k(pa1, vfB, O, 0, 0, 0);
      }
    }
    __syncthreads();
    cur ^= 1;
  }

  // row-sum over the 4 gq groups -> per-lane c holds row q=c's sum
  psum += __shfl_xor(psum, 16);
  psum += __shfl_xor(psum, 32);

  // direct partial writes (waves own distinct q-tiles; no inter-wave merge)
  float* pO = partO + (((size_t)z * 32 + qt) * 8 + h) * 768;
#pragma unroll
  for (int r = 0; r < 4; ++r) {
    const int q = 4 * gq + r;
    pO[q * 48 + c] = O0[r];
    pO[q * 48 + 16 + c] = O1[r];
    pO[q * 48 + 32 + c] = O2[r];
  }
  if (gq == 0)
    partL[(((size_t)z * 32 + qt) * 8 + h) * 16 + c] = psum;
}

// Combine 8 key-split partials, apply 1/l and gate.
__global__ __launch_bounds__(256) void attn_merge(
    const float* __restrict__ partO, const float* __restrict__ partL,
    const float* __restrict__ gate, u16* __restrict__ attng) {
  const int qt = blockIdx.x, h = blockIdx.y;
  for (int idx = threadIdx.x; idx < 768; idx += 256) {
    const int q = idx / 48, d = idx % 48;
    float O = 0.f, L = 0.f;
#pragma unroll
    for (int z = 0; z < 8; ++z) {
      O += partO[(((size_t)z * 32 + qt) * 8 + h) * 768 + idx];
      L += partL[(((size_t)z * 32 + qt) * 8 + h) * 16 + q];
    }
    const size_t off = (size_t)(qt * 16 + q) * 384 + h * 48 + d;
    attng[off] = f2bf(O / L * gate[off]);
  }
}

// Merge T1 split-K partials + bias + residual -> out_res.
__global__ __launch_bounds__(256) void merge_res(
    const float* __restrict__ pT1, const float* __restrict__ res2,
    const float* __restrict__ rtb2, float* __restrict__ out_res) {
  const int i = blockIdx.x * 256 + threadIdx.x;
  const int n0 = (i * 4) % 384;
  f32x4 v = *(const f32x4*)(res2 + (size_t)i * 4);
#pragma unroll
  for (int z = 0; z < 4; ++z) {
    const f32x4 pz = *(const f32x4*)(pT1 + (size_t)z * 512 * 384 + (size_t)i * 4);
#pragma unroll
    for (int r = 0; r < 4; ++r) v[r] += pz[r];
  }
  const f32x4 b = *(const f32x4*)(rtb2 + n0);
#pragma unroll
  for (int r = 0; r < 4; ++r) v[r] += b[r];
  *(f32x4*)(out_res + (size_t)i * 4) = v;
}

// ---------------------------------------------------------------------------
extern "C" void kernel_launch(void* const* d_in, const int* in_sizes, int n_in,
                              void* d_out, int out_size, void* d_ws, size_t ws_size,
                              hipStream_t stream) {
  (void)in_sizes; (void)n_in; (void)out_size; (void)ws_size;
  const float* original = (const float*)d_in[0];
  const float* resampled = (const float*)d_in[1];
  const float* amask = (const float*)d_in[2];
  const float* qn_s = (const float*)d_in[5];
  const float* qn_o = (const float*)d_in[6];
  const float* dn_s = (const float*)d_in[7];
  const float* dn_o = (const float*)d_in[8];
  const float* w_q = (const float*)d_in[9];
  const float* w_k = (const float*)d_in[10];
  const float* w_v = (const float*)d_in[11];
  const float* w_g = (const float*)d_in[12];
  const float* b_g = (const float*)d_in[13];
  const float* w_o = (const float*)d_in[14];
  const float* b_o = (const float*)d_in[15];
  const float* rt_s = (const float*)d_in[16];
  const float* rt_o = (const float*)d_in[17];
  const float* rtw1 = (const float*)d_in[18];
  const float* rtb1 = (const float*)d_in[19];
  const float* rtw2 = (const float*)d_in[20];
  const float* rtb2 = (const float*)d_in[21];
  const float* ot_s = (const float*)d_in[22];
  const float* ot_o = (const float*)d_in[23];
  const float* otw1 = (const float*)d_in[24];
  const float* otb1 = (const float*)d_in[25];
  const float* otw2 = (const float*)d_in[26];
  const float* otb2 = (const float*)d_in[27];

  float* out_res = (float*)d_out;
  float* out_orig = out_res + 512 * 384;

  char* p = (char*)d_ws;
  auto alloc = [&](size_t n) {
    void* r = (void*)p;
    p += (n + 255) & ~(size_t)255;
    return r;
  };
  u16* Kh = (u16*)alloc((size_t)8 * 4096 * 64 * 2);  // padded K (memset 0)
  u16* Qb = (u16*)alloc((size_t)8 * 512 * 64 * 2);   // padded Q (memset 0, adjacent)
  u16* dinb = (u16*)alloc(4096 * 384 * 2);
  u16* otin = (u16*)alloc(4096 * 384 * 2);
  u16* qin = (u16*)alloc(512 * 384 * 2);
  u16* Vt = (u16*)alloc((size_t)384 * VSTR * 2);
  float* gateb = (float*)alloc(512 * 384 * 4);
  u16* attng = (u16*)alloc(512 * 384 * 2);
  float* res2 = (float*)alloc(512 * 384 * 4);
  u16* tin = (u16*)alloc(512 * 384 * 2);
  u16* H1 = (u16*)alloc(512 * 1536 * 2);
  u16* H2 = (u16*)alloc((size_t)4096 * 1536 * 2);
  float* partT1 = (float*)alloc((size_t)4 * 512 * 384 * 4);
  float* partO = (float*)alloc((size_t)8 * 32 * 8 * 768 * 4);
  float* partL = (float*)alloc((size_t)8 * 32 * 8 * 16 * 4);
  u16* mbitsB = (u16*)alloc((size_t)8 * 512 * 512);  // 2MB bitmask
  u16* BtKV = (u16*)alloc(768 * 384 * 2);
  u16* BtQG = (u16*)alloc(768 * 384 * 2);
  u16* OwT = (u16*)alloc(384 * 384 * 2);
  u16* Rt1T = (u16*)alloc(1536 * 384 * 2);
  u16* Rt2T = (u16*)alloc(384 * 1536 * 2);
  u16* Ot1T = (u16*)alloc(1536 * 384 * 2);
  u16* Ot2T = (u16*)alloc(384 * 1536 * 2);

  hipMemsetAsync(Kh, 0, (size_t)8 * 4096 * 64 * 2 + (size_t)8 * 512 * 64 * 2, stream);

  mask_bits<<<4096, 256, 0, stream>>>(amask, mbitsB);

  {
    TBatch tb{};
    const float qscale = 0.14433756729740643f;  // 48^-0.5
    const float* ins[9] = {w_q, w_g, w_k, w_v, w_o, rtw1, rtw2, otw1, otw2};
    u16* outs[9] = {BtQG, BtQG + 384 * 384, BtKV, BtKV + 384 * 384, OwT,
                    Rt1T, Rt2T, Ot1T, Ot2T};
    const int Ks[9] = {384, 384, 384, 384, 384, 384, 1536, 384, 1536};
    const int Ns[9] = {384, 384, 384, 384, 384, 1536, 384, 1536, 384};
    int off = 0;
    for (int j = 0; j < 9; ++j) {
      tb.in[j] = ins[j]; tb.out[j] = outs[j];
      tb.K[j] = Ks[j]; tb.N[j] = Ns[j];
      tb.scale[j] = (j == 0) ? qscale : 1.f;
      tb.boff[j] = off;
      off += (Ns[j] >> 5) * (Ks[j] >> 5);
    }
    tb.boff[9] = off;
    transpose_all<<<off, dim3(32, 8), 0, stream>>>(tb);
  }

  ln_all<<<4608, 128, 0, stream>>>(original, resampled, dn_s, dn_o, dinb,
                                   ot_s, ot_o, otin, qn_s, qn_o, qin);

  {  // P1: K/V projections (128x64 tile -> 384 blocks, 3/CU)
    GArgs a{};
    a.A = dinb; a.Bt = BtKV; a.M = 4096; a.N = 768; a.K = 384; a.Kld = 384;
    a.outb = Kh; a.outb2 = Vt;
    gemm_bt<128, 64, 2><<<dim3(12, 32), 256, 0, stream>>>(a);
  }
  {  // P2: Q/gate projections
    GArgs a{};
    a.A = qin; a.Bt = BtQG; a.M = 512; a.N = 768; a.K = 384; a.Kld = 384;
    a.outb = Qb; a.outf = gateb; a.bias2 = b_g;
    gemm_bt<64, 64, 3><<<dim3(12, 8), 256, 0, stream>>>(a);
  }

  attn_kernel<<<dim3(8, 8, 8), 256, 0, stream>>>(
      Kh, Qb, Vt, (const unsigned char*)mbitsB, partO, partL);
  attn_merge<<<dim3(32, 8), 256, 0, stream>>>(partO, partL, gateb, attng);

  {  // P3: output projection + residual -> res2
    GArgs a{};
    a.A = attng; a.Bt = OwT; a.M = 512; a.N = 384; a.K = 384; a.Kld = 384;
    a.bias = b_o; a.residual = resampled; a.outf = res2;
    gemm_bt<64, 64, 1><<<dim3(6, 8), 256, 0, stream>>>(a);
  }
  ln_kernel<<<512, 128, 0, stream>>>(res2, rt_s, rt_o, tin);
  {  // T1a
    GArgs a{};
    a.A = tin; a.Bt = Rt1T; a.M = 512; a.N = 1536; a.K = 384; a.Kld = 384;
    a.bias = rtb1; a.outb = H1;
    gemm_bt<64, 64, 0><<<dim3(24, 8), 256, 0, stream>>>(a);
  }
  {  // T1b split-K=4 -> partT1
    GArgs a{};
    a.A = H1; a.Bt = Rt2T; a.M = 512; a.N = 384; a.K = 384; a.Kld = 1536;
    a.outf = partT1;
    gemm_bt<64, 64, 4><<<dim3(6, 8, 4), 256, 0, stream>>>(a);
  }
  {  // T2a (128x64 tile -> 768 blocks, 3/CU)
    GArgs a{};
    a.A = otin; a.Bt = Ot1T; a.M = 4096; a.N = 1536; a.K = 384; a.Kld = 384;
    a.bias = otb1; a.outb = H2;
    gemm_bt<128, 64, 0><<<dim3(24, 32), 256, 0, stream>>>(a);
  }
  {  // T2b direct
    GArgs a{};
    a.A = H2; a.Bt = Ot2T; a.M = 4096; a.N = 384; a.K = 1536; a.Kld = 1536;
    a.bias = otb2; a.residual = original; a.outf = out_orig;
    gemm_bt<64, 64, 1><<<dim3(6, 64), 256, 0, stream>>>(a);
  }
  merge_res<<<192, 256, 0, stream>>>(partT1, res2, rtb2, out_res);
}

// Round 10
// 244.988 us; speedup vs baseline: 1.1907x; 1.0666x over previous
//
#include <hip/hip_runtime.h>
#include <hip/hip_bf16.h>
#include <cstdint>

typedef unsigned short u16;
typedef __attribute__((ext_vector_type(8))) __bf16 bf16x8;
typedef __attribute__((ext_vector_type(4))) float f32x4;
typedef __attribute__((ext_vector_type(4))) short s16x4;
typedef __attribute__((ext_vector_type(4))) unsigned u32x4;

#define VSTR 4160  // padded Vt row stride

__device__ __forceinline__ u16 f2bf(float f) {
  union { float f; unsigned u; } v; v.f = f;
  unsigned r = (v.u + 0x7FFFu + ((v.u >> 16) & 1u)) >> 16;
  return (u16)r;
}

__device__ __forceinline__ void gll16(const u16* gp, u16* lp) {
  auto g1 = reinterpret_cast<const __attribute__((address_space(1))) void*>(
      reinterpret_cast<uintptr_t>(gp));
  auto l3 = reinterpret_cast<__attribute__((address_space(3))) void*>(
      reinterpret_cast<uintptr_t>(lp));
  __builtin_amdgcn_global_load_lds(g1, l3, 16, 0, 0);
}

// ---------------------------------------------------------------------------
// Fused preprocessing kernel. Segmented grid (256 threads/block).
// Segment boundaries (BLOCK indices) — transpose tile count is
// sum_j (N_j/32)*(K_j/32) = 5*144 + 4*576 = 3024 (NOT 153 — round-9 bug):
//  [0,4096)        mask f32 -> bitmask
//  [4096,6400)     input LayerNorms (2 rows/block)
//  [6400,9424)     9 weight transposes (3024 tiles)
//  [9424,9680)     Kh d-pad zero (cols 48..63)
//  [9680,9712)     Qb d-pad zero
//  [9712,9904)     res2     = resampled + b_o    (basis for P3 atomics)
//  [9904,11440)    out_orig = original + otb2    (basis for T2b atomics)
// ---------------------------------------------------------------------------
#define PREP_B0 4096
#define PREP_B1 6400
#define PREP_B2 9424
#define PREP_B3 9680
#define PREP_B4 9712
#define PREP_B5 9904
#define PREP_B6 11440

struct TBatch {
  const float* in[9];
  u16* out[9];
  int K[9], N[9];
  float scale[9];
  int boff[10];
};

struct PrepArgs {
  const float* mask; u16* mb;
  const float* orig; const float* resam;
  const float* dn_s; const float* dn_o; u16* dinb;
  const float* ot_s; const float* ot_o; u16* otin;
  const float* qn_s; const float* qn_o; u16* qin;
  TBatch tb;
  u16* Kh; u16* Qb;
  const float* b_o; float* res2;
  const float* otb2; float* out_orig;
};

__global__ __launch_bounds__(256) void prep_kernel(PrepArgs a) {
  const int bid = blockIdx.x;
  const int tid = threadIdx.x;
  __shared__ float tile[32][33];
  __shared__ float red[2][2][2];

  if (bid < PREP_B0) {  // ---- mask -> bits ----
    const int t = bid * 256 + tid;
    const float* src = a.mask + (size_t)t * 16;
    unsigned b = 0;
#pragma unroll
    for (int j = 0; j < 4; ++j) {
      const f32x4 v = *(const f32x4*)(src + 4 * j);
#pragma unroll
      for (int k = 0; k < 4; ++k) b |= (v[k] != 0.f ? 1u : 0u) << (4 * j + k);
    }
    a.mb[t] = (u16)b;
  } else if (bid < PREP_B1) {  // ---- input LayerNorms, 2 rows/block ----
    const int lb = bid - PREP_B0;
    const int sub = tid >> 7;
    const int t = tid & 127;
    const int row = lb * 2 + sub;
    const bool isOrig = row < 4096;
    const float* xr = isOrig ? a.orig + (size_t)row * 384
                             : a.resam + (size_t)(row - 4096) * 384;
    float v0 = xr[t], v1 = xr[t + 128], v2 = xr[t + 256];
    float sum = v0 + v1 + v2;
    float sq = v0 * v0 + v1 * v1 + v2 * v2;
#pragma unroll
    for (int off = 32; off > 0; off >>= 1) {
      sum += __shfl_xor(sum, off);
      sq += __shfl_xor(sq, off);
    }
    if ((tid & 63) == 0) {
      red[sub][(tid >> 6) & 1][0] = sum;
      red[sub][(tid >> 6) & 1][1] = sq;
    }
    __syncthreads();
    sum = red[sub][0][0] + red[sub][1][0];
    sq = red[sub][0][1] + red[sub][1][1];
    const float mu = sum * (1.f / 384.f);
    const float rstd = rsqrtf(sq * (1.f / 384.f) - mu * mu + 1e-5f);
#pragma unroll
    for (int j = 0; j < 3; ++j) {
      const int cc = t + 128 * j;
      const float xv = (j == 0 ? v0 : (j == 1 ? v1 : v2));
      const float xn = (xv - mu) * rstd;
      if (isOrig) {
        a.dinb[(size_t)row * 384 + cc] = f2bf(a.dn_s[cc] * xn + a.dn_o[cc]);
        a.otin[(size_t)row * 384 + cc] = f2bf(a.ot_s[cc] * xn + a.ot_o[cc]);
      } else {
        a.qin[(size_t)(row - 4096) * 384 + cc] = f2bf(a.qn_s[cc] * xn + a.qn_o[cc]);
      }
    }
  } else if (bid < PREP_B2) {  // ---- weight transposes (3024 tiles) ----
    const int b = bid - PREP_B1;
    int j = 0;
    while (j < 8 && b >= a.tb.boff[j + 1]) ++j;
    const int lb = b - a.tb.boff[j];
    const int NB = a.tb.N[j] >> 5;
    const int bx = lb % NB, by = lb / NB;
    const float* in = a.tb.in[j];
    u16* out = a.tb.out[j];
    const int K = a.tb.K[j], N = a.tb.N[j];
    const float scale = a.tb.scale[j];
    const int tx = tid & 31, ty = tid >> 5;
    const int nb = bx * 32, kb = by * 32;
#pragma unroll
    for (int i = 0; i < 4; ++i)
      tile[ty + 8 * i][tx] = in[(size_t)(kb + ty + 8 * i) * N + nb + tx];
    __syncthreads();
#pragma unroll
    for (int i = 0; i < 4; ++i)
      out[(size_t)(nb + ty + 8 * i) * K + kb + tx] = f2bf(tile[tx][ty + 8 * i] * scale);
  } else if (bid < PREP_B3) {  // ---- Kh pad zero ----
    const int gi = (bid - PREP_B2) * 256 + tid;  // [0, 65536)
    const int r = gi >> 1, half = gi & 1;        // r in [0, 8*4096)
    u32x4 z{0u, 0u, 0u, 0u};
    *(u32x4*)(a.Kh + (size_t)r * 64 + 48 + half * 8) = z;
  } else if (bid < PREP_B4) {  // ---- Qb pad zero ----
    const int gi = (bid - PREP_B3) * 256 + tid;  // [0, 8192)
    const int r = gi >> 1, half = gi & 1;        // r in [0, 8*512)
    u32x4 z{0u, 0u, 0u, 0u};
    *(u32x4*)(a.Qb + (size_t)r * 64 + 48 + half * 8) = z;
  } else if (bid < PREP_B5) {  // ---- res2 init ----
    const int i = (bid - PREP_B4) * 256 + tid;   // [0, 49152)
    const int n0 = (i * 4) % 384;
    f32x4 v = *(const f32x4*)(a.resam + (size_t)i * 4);
    const f32x4 b = *(const f32x4*)(a.b_o + n0);
#pragma unroll
    for (int r = 0; r < 4; ++r) v[r] += b[r];
    *(f32x4*)(a.res2 + (size_t)i * 4) = v;
  } else {  // ---- out_orig init ----
    const int i = (bid - PREP_B5) * 256 + tid;   // [0, 393216)
    const int n0 = (i * 4) % 384;
    f32x4 v = *(const f32x4*)(a.orig + (size_t)i * 4);
    const f32x4 b = *(const f32x4*)(a.otb2 + n0);
#pragma unroll
    for (int r = 0; r < 4; ++r) v[r] += b[r];
    *(f32x4*)(a.out_orig + (size_t)i * 4) = v;
  }
}

// ---------------------------------------------------------------------------
// rt-path LN: reads res2 (after P3 atomics), writes tin (bf16 LN output) and
// out_res = res2 + rtb2 (basis for T1b atomic split-K). 2 rows/block.
// ---------------------------------------------------------------------------
__global__ __launch_bounds__(256) void ln_rt(
    const float* __restrict__ res2, const float* __restrict__ s1,
    const float* __restrict__ o1, const float* __restrict__ rtb2,
    u16* __restrict__ tin, float* __restrict__ out_res) {
  const int sub = threadIdx.x >> 7;
  const int t = threadIdx.x & 127;
  const int row = blockIdx.x * 2 + sub;
  __shared__ float red[2][2][2];
  const float* xr = res2 + (size_t)row * 384;
  float v0 = xr[t], v1 = xr[t + 128], v2 = xr[t + 256];
  float sum = v0 + v1 + v2;
  float sq = v0 * v0 + v1 * v1 + v2 * v2;
#pragma unroll
  for (int off = 32; off > 0; off >>= 1) {
    sum += __shfl_xor(sum, off);
    sq += __shfl_xor(sq, off);
  }
  if ((threadIdx.x & 63) == 0) {
    red[sub][(threadIdx.x >> 6) & 1][0] = sum;
    red[sub][(threadIdx.x >> 6) & 1][1] = sq;
  }
  __syncthreads();
  sum = red[sub][0][0] + red[sub][1][0];
  sq = red[sub][0][1] + red[sub][1][1];
  const float mu = sum * (1.f / 384.f);
  const float rstd = rsqrtf(sq * (1.f / 384.f) - mu * mu + 1e-5f);
#pragma unroll
  for (int j = 0; j < 3; ++j) {
    const int cc = t + 128 * j;
    const float xv = (j == 0 ? v0 : (j == 1 ? v1 : v2));
    tin[(size_t)row * 384 + cc] = f2bf(s1[cc] * ((xv - mu) * rstd) + o1[cc]);
    out_res[(size_t)row * 384 + cc] = xv + rtb2[cc];
  }
}

// ---------------------------------------------------------------------------
// GEMM: C[M][N] = A[M][K] (bf16, ld=Kld) * Bt[N][K]^T. BK=64, dbuf gll16, XOR LDS.
// EPI: 0 bf16 relu(acc+bias); 5 atomicAdd(outf, acc) [split-K via blockIdx.z];
//      7 fused P1P2 (y<32: Kh/Vt; y>=32: Qb/gate).
// ---------------------------------------------------------------------------
struct GArgs {
  const u16* A; const u16* Bt; const u16* Bt2;
  int M, N, K, Kld;
  const float* bias; const float* bias2;
  float* outf; u16* outb; u16* outb2; u16* outb3;
};

template <int BM, int BN, int EPI>
__global__ __launch_bounds__(256, (BM == 128 ? 3 : 4)) void gemm_bt(GArgs g) {
  constexpr int MT = BM / 32, NT = BN / 32;
  const int tid = threadIdx.x;
  const int w = tid >> 6;
  const int lane = tid & 63;
  const int gq = lane >> 4, c = lane & 15;
  const int brow = blockIdx.y * BM, bcol = blockIdx.x * BN;
  const int wm = (w >> 1) * (BM / 2), wn = (w & 1) * (BN / 2);
  __shared__ u16 As[2][BM][64];
  __shared__ u16 Bs[2][BN][64];
  const int K = g.K;
  const int Kld = g.Kld;
  const size_t koff = (size_t)blockIdx.z * K;
  const u16* BT = (EPI == 7 && blockIdx.y >= 32) ? g.Bt2 : g.Bt;

  f32x4 acc[MT][NT];
#pragma unroll
  for (int mt = 0; mt < MT; ++mt)
#pragma unroll
    for (int nt = 0; nt < NT; ++nt)
#pragma unroll
      for (int r = 0; r < 4; ++r) acc[mt][nt][r] = 0.f;

  const int srow = lane >> 3;
  const int schunk = (lane & 7) ^ srow;
  const u16* aSrc = g.A + (size_t)(brow + w * (BM / 4) + srow) * Kld + koff + schunk * 8;
  const u16* bSrc = BT + (size_t)(bcol + w * (BN / 4) + srow) * Kld + koff + schunk * 8;

  auto STAGE = [&](int buf, int k0) {
#pragma unroll
    for (int i = 0; i < BM / 32; ++i)
      gll16(aSrc + (size_t)(8 * i) * Kld + k0, &As[buf][w * (BM / 4) + i * 8][0]);
#pragma unroll
    for (int i = 0; i < BN / 32; ++i)
      gll16(bSrc + (size_t)(8 * i) * Kld + k0, &Bs[buf][w * (BN / 4) + i * 8][0]);
  };

  auto COMPUTE = [&](int buf) {
#pragma unroll
    for (int ks = 0; ks < 2; ++ks) {
      bf16x8 af[MT], bfv[NT];
#pragma unroll
      for (int mt = 0; mt < MT; ++mt) {
        const int row = wm + mt * 16 + c;
        const int ch = ((ks << 2) | gq) ^ (row & 7);
        af[mt] = *(const bf16x8*)&As[buf][row][ch * 8];
      }
#pragma unroll
      for (int nt = 0; nt < NT; ++nt) {
        const int row = wn + nt * 16 + c;
        const int ch = ((ks << 2) | gq) ^ (row & 7);
        bfv[nt] = *(const bf16x8*)&Bs[buf][row][ch * 8];
      }
#pragma unroll
      for (int mt = 0; mt < MT; ++mt)
#pragma unroll
        for (int nt = 0; nt < NT; ++nt)
          acc[mt][nt] =
              __builtin_amdgcn_mfma_f32_16x16x32_bf16(af[mt], bfv[nt], acc[mt][nt], 0, 0, 0);
    }
  };

  const int NTILES = K >> 6;
  STAGE(0, 0);
  __syncthreads();
  int cur = 0;
  for (int t = 0; t < NTILES; ++t) {
    if (t + 1 < NTILES) STAGE(cur ^ 1, (t + 1) << 6);
    COMPUTE(cur);
    __syncthreads();
    cur ^= 1;
  }

  const int N = g.N;
#pragma unroll
  for (int mt = 0; mt < MT; ++mt) {
#pragma unroll
    for (int nt = 0; nt < NT; ++nt) {
      const int n = bcol + wn + nt * 16 + c;
#pragma unroll
      for (int r = 0; r < 4; ++r) {
        const int m = brow + wm + mt * 16 + 4 * gq + r;
        const float v = acc[mt][nt][r];
        if (EPI == 0) {
          g.outb[(size_t)m * N + n] = f2bf(fmaxf(v + g.bias[n], 0.f));
        } else if (EPI == 5) {
          atomicAdd(g.outf + (size_t)m * N + n, v);
        } else if (EPI == 7) {
          if (m < 4096) {
            if (n < 384)
              g.outb[(size_t)(n / 48) * 4096 * 64 + (size_t)m * 64 + (n % 48)] = f2bf(v);
            else
              g.outb2[(size_t)(n - 384) * VSTR + m] = f2bf(v);
          } else {
            const int mq = m - 4096;
            if (n < 384)
              g.outb3[(size_t)(n / 48) * 512 * 64 + (size_t)mq * 64 + (n % 48)] = f2bf(v);
            else {
              const float sg = v + g.bias2[n - 384];
              g.outf[(size_t)mq * 384 + (n - 384)] = 1.f / (1.f + __expf(-sg));
            }
          }
        }
      }
    }
  }
}

// ---------------------------------------------------------------------------
// Attention (round-8 verified): GEMM-style LDS staging, bitmask,
// p = bit ? exp(s) : 0. Grid (8 qg, 8 h, 8 z), 4 waves.
// ---------------------------------------------------------------------------
__global__ __launch_bounds__(256, 2) void attn_kernel(
    const u16* __restrict__ Kh, const u16* __restrict__ Qb, const u16* __restrict__ Vt,
    const unsigned char* __restrict__ mbits, float* __restrict__ partO,
    float* __restrict__ partL) {
  const int tid = threadIdx.x;
  const int w = tid >> 6;
  const int lane = tid & 63;
  const int gq = lane >> 4, c = lane & 15;
  const int qg = blockIdx.x, h = blockIdx.y, z = blockIdx.z;
  const int qt = qg * 4 + w;
  const int kb = z * 512;

  __shared__ u16 Ks[2][128][64];
  __shared__ u16 Vs[2][48][128];

  const u16* qrow = Qb + ((size_t)h * 512 + qt * 16 + c) * 64;
  const bf16x8 qf0 = *(const bf16x8*)(qrow + 8 * gq);
  const bf16x8 qf1 = *(const bf16x8*)(qrow + 32 + 8 * gq);

  const unsigned char* mrow = mbits + ((size_t)h * 512 + qt * 16 + c) * 512 + z * 64;
  u32x4 mbAll[4];
#pragma unroll
  for (int ch = 0; ch < 4; ++ch) mbAll[ch] = *(const u32x4*)(mrow + ch * 16);

  const int krow8 = lane >> 3;
  const int kch = (lane & 7) ^ krow8;
  const u16* kbase = Kh + (size_t)h * 4096 * 64;
  const int vrow4 = lane >> 4;
  const int vk16 = lane & 15;

  auto STAGE = [&](int buf, int ch) {
    const int k0 = kb + ch * 128;
#pragma unroll
    for (int j = 0; j < 4; ++j) {
      gll16(kbase + (size_t)(k0 + w * 32 + j * 8 + krow8) * 64 + kch * 8,
            &Ks[buf][w * 32 + j * 8][0]);
    }
#pragma unroll
    for (int j = 0; j < 3; ++j) {
      const int d = w * 12 + j * 4 + vrow4;
      const int sk = vk16 ^ (d & 15);
      gll16(Vt + (size_t)(h * 48 + d) * VSTR + k0 + sk * 8, &Vs[buf][w * 12 + j * 4][0]);
    }
  };

  f32x4 O0, O1, O2;
#pragma unroll
  for (int r = 0; r < 4; ++r) { O0[r] = 0.f; O1[r] = 0.f; O2[r] = 0.f; }
  float psum = 0.f;
  f32x4 z4;
#pragma unroll
  for (int r = 0; r < 4; ++r) z4[r] = 0.f;

  STAGE(0, 0);
  __syncthreads();
  int cur = 0;
  for (int ch = 0; ch < 4; ++ch) {
    if (ch + 1 < 4) STAGE(cur ^ 1, ch + 1);
#pragma unroll
    for (int s = 0; s < 4; ++s) {
      const int keyA = s * 32 + c;
      const int keyB = keyA + 16;
      const bf16x8 kA0 = *(const bf16x8*)&Ks[cur][keyA][(gq ^ (keyA & 7)) * 8];
      const bf16x8 kA1 = *(const bf16x8*)&Ks[cur][keyA][((4 + gq) ^ (keyA & 7)) * 8];
      const bf16x8 kB0 = *(const bf16x8*)&Ks[cur][keyB][(gq ^ (keyB & 7)) * 8];
      const bf16x8 kB1 = *(const bf16x8*)&Ks[cur][keyB][((4 + gq) ^ (keyB & 7)) * 8];

      f32x4 s0 = __builtin_amdgcn_mfma_f32_16x16x32_bf16(kA0, qf0, z4, 0, 0, 0);
      s0 = __builtin_amdgcn_mfma_f32_16x16x32_bf16(kA1, qf1, s0, 0, 0, 0);
      f32x4 s1 = __builtin_amdgcn_mfma_f32_16x16x32_bf16(kB0, qf0, z4, 0, 0, 0);
      s1 = __builtin_amdgcn_mfma_f32_16x16x32_bf16(kB1, qf1, s1, 0, 0, 0);

      const unsigned word = mbAll[ch][s];
      const unsigned wd0 = word >> (4 * gq);
      const unsigned wd1 = word >> (16 + 4 * gq);
      float p0[4], p1[4];
#pragma unroll
      for (int r = 0; r < 4; ++r) {
        p0[r] = ((wd0 >> r) & 1u) ? __expf(s0[r]) : 0.f;
        p1[r] = ((wd1 >> r) & 1u) ? __expf(s1[r]) : 0.f;
        psum += p0[r] + p1[r];
      }
      s16x4 pa0, pa1;
      ((unsigned*)&pa0)[0] = __builtin_amdgcn_perm(__builtin_bit_cast(unsigned, p0[1]),
                                                   __builtin_bit_cast(unsigned, p0[0]), 0x07060302u);
      ((unsigned*)&pa0)[1] = __builtin_amdgcn_perm(__builtin_bit_cast(unsigned, p0[3]),
                                                   __builtin_bit_cast(unsigned, p0[2]), 0x07060302u);
      ((unsigned*)&pa1)[0] = __builtin_amdgcn_perm(__builtin_bit_cast(unsigned, p1[1]),
                                                   __builtin_bit_cast(unsigned, p1[0]), 0x07060302u);
      ((unsigned*)&pa1)[1] = __builtin_amdgcn_perm(__builtin_bit_cast(unsigned, p1[3]),
                                                   __builtin_bit_cast(unsigned, p1[2]), 0x07060302u);

#pragma unroll
      for (int nt = 0; nt < 3; ++nt) {
        const int row = nt * 16 + c;
        const int klA = s * 32 + 4 * gq;
        const int klB = klA + 16;
        const s16x4 vfA = *(const s16x4*)&Vs[cur][row][(((klA >> 3) ^ c) << 3) + (gq & 1) * 4];
        const s16x4 vfB = *(const s16x4*)&Vs[cur][row][(((klB >> 3) ^ c) << 3) + (gq & 1) * 4];
        f32x4& O = (nt == 0 ? O0 : (nt == 1 ? O1 : O2));
        O = __builtin_amdgcn_mfma_f32_16x16x16bf16_1k(pa0, vfA, O, 0, 0, 0);
        O = __builtin_amdgcn_mfma_f32_16x16x16bf16_1k(pa1, vfB, O, 0, 0, 0);
      }
    }
    __syncthreads();
    cur ^= 1;
  }

  psum += __shfl_xor(psum, 16);
  psum += __shfl_xor(psum, 32);

  float* pO = partO + (((size_t)z * 32 + qt) * 8 + h) * 768;
#pragma unroll
  for (int r = 0; r < 4; ++r) {
    const int q = 4 * gq + r;
    pO[q * 48 + c] = O0[r];
    pO[q * 48 + 16 + c] = O1[r];
    pO[q * 48 + 32 + c] = O2[r];
  }
  if (gq == 0)
    partL[(((size_t)z * 32 + qt) * 8 + h) * 16 + c] = psum;
}

// Combine 8 key-split partials, apply 1/l and gate.
__global__ __launch_bounds__(256) void attn_merge(
    const float* __restrict__ partO, const float* __restrict__ partL,
    const float* __restrict__ gate, u16* __restrict__ attng) {
  const int qt = blockIdx.x, h = blockIdx.y;
  for (int idx = threadIdx.x; idx < 768; idx += 256) {
    const int q = idx / 48, d = idx % 48;
    float O = 0.f, L = 0.f;
#pragma unroll
    for (int z = 0; z < 8; ++z) {
      O += partO[(((size_t)z * 32 + qt) * 8 + h) * 768 + idx];
      L += partL[(((size_t)z * 32 + qt) * 8 + h) * 16 + q];
    }
    const size_t off = (size_t)(qt * 16 + q) * 384 + h * 48 + d;
    attng[off] = f2bf(O / L * gate[off]);
  }
}

// ---------------------------------------------------------------------------
extern "C" void kernel_launch(void* const* d_in, const int* in_sizes, int n_in,
                              void* d_out, int out_size, void* d_ws, size_t ws_size,
                              hipStream_t stream) {
  (void)in_sizes; (void)n_in; (void)out_size; (void)ws_size;
  const float* original = (const float*)d_in[0];
  const float* resampled = (const float*)d_in[1];
  const float* amask = (const float*)d_in[2];
  const float* qn_s = (const float*)d_in[5];
  const float* qn_o = (const float*)d_in[6];
  const float* dn_s = (const float*)d_in[7];
  const float* dn_o = (const float*)d_in[8];
  const float* w_q = (const float*)d_in[9];
  const float* w_k = (const float*)d_in[10];
  const float* w_v = (const float*)d_in[11];
  const float* w_g = (const float*)d_in[12];
  const float* b_g = (const float*)d_in[13];
  const float* w_o = (const float*)d_in[14];
  const float* b_o = (const float*)d_in[15];
  const float* rt_s = (const float*)d_in[16];
  const float* rt_o = (const float*)d_in[17];
  const float* rtw1 = (const float*)d_in[18];
  const float* rtb1 = (const float*)d_in[19];
  const float* rtw2 = (const float*)d_in[20];
  const float* rtb2 = (const float*)d_in[21];
  const float* ot_s = (const float*)d_in[22];
  const float* ot_o = (const float*)d_in[23];
  const float* otw1 = (const float*)d_in[24];
  const float* otb1 = (const float*)d_in[25];
  const float* otw2 = (const float*)d_in[26];
  const float* otb2 = (const float*)d_in[27];

  float* out_res = (float*)d_out;
  float* out_orig = out_res + 512 * 384;

  char* p = (char*)d_ws;
  auto alloc = [&](size_t n) {
    void* r = (void*)p;
    p += (n + 255) & ~(size_t)255;
    return r;
  };
  u16* Kh = (u16*)alloc((size_t)8 * 4096 * 64 * 2);
  u16* Qb = (u16*)alloc((size_t)8 * 512 * 64 * 2);
  u16* dinb = (u16*)alloc(4096 * 384 * 2);   // qin directly after (stacked A)
  u16* qin = (u16*)alloc(512 * 384 * 2);
  u16* otin = (u16*)alloc(4096 * 384 * 2);
  u16* Vt = (u16*)alloc((size_t)384 * VSTR * 2);
  float* gateb = (float*)alloc(512 * 384 * 4);
  u16* attng = (u16*)alloc(512 * 384 * 2);
  float* res2 = (float*)alloc(512 * 384 * 4);
  u16* tin = (u16*)alloc(512 * 384 * 2);
  u16* H1 = (u16*)alloc(512 * 1536 * 2);
  u16* H2 = (u16*)alloc((size_t)4096 * 1536 * 2);
  float* partO = (float*)alloc((size_t)8 * 32 * 8 * 768 * 4);
  float* partL = (float*)alloc((size_t)8 * 32 * 8 * 16 * 4);
  u16* mbitsB = (u16*)alloc((size_t)8 * 512 * 512);
  u16* BtKV = (u16*)alloc(768 * 384 * 2);
  u16* BtQG = (u16*)alloc(768 * 384 * 2);
  u16* OwT = (u16*)alloc(384 * 384 * 2);
  u16* Rt1T = (u16*)alloc(1536 * 384 * 2);
  u16* Rt2T = (u16*)alloc(384 * 1536 * 2);
  u16* Ot1T = (u16*)alloc(1536 * 384 * 2);
  u16* Ot2T = (u16*)alloc(384 * 1536 * 2);

  // ---- 1: prep (mask bits + LNs + transposes + pads + output bases) ----
  {
    PrepArgs pa{};
    pa.mask = amask; pa.mb = mbitsB;
    pa.orig = original; pa.resam = resampled;
    pa.dn_s = dn_s; pa.dn_o = dn_o; pa.dinb = dinb;
    pa.ot_s = ot_s; pa.ot_o = ot_o; pa.otin = otin;
    pa.qn_s = qn_s; pa.qn_o = qn_o; pa.qin = qin;
    const float qscale = 0.14433756729740643f;  // 48^-0.5
    const float* ins[9] = {w_q, w_g, w_k, w_v, w_o, rtw1, rtw2, otw1, otw2};
    u16* outs[9] = {BtQG, BtQG + 384 * 384, BtKV, BtKV + 384 * 384, OwT,
                    Rt1T, Rt2T, Ot1T, Ot2T};
    const int Ks[9] = {384, 384, 384, 384, 384, 384, 1536, 384, 1536};
    const int Ns[9] = {384, 384, 384, 384, 384, 1536, 384, 1536, 384};
    int off = 0;
    for (int j = 0; j < 9; ++j) {
      pa.tb.in[j] = ins[j]; pa.tb.out[j] = outs[j];
      pa.tb.K[j] = Ks[j]; pa.tb.N[j] = Ns[j];
      pa.tb.scale[j] = (j == 0) ? qscale : 1.f;
      pa.tb.boff[j] = off;
      off += (Ns[j] >> 5) * (Ks[j] >> 5);
    }
    pa.tb.boff[9] = off;  // 3024 — must equal PREP_B2 - PREP_B1
    pa.Kh = Kh; pa.Qb = Qb;
    pa.b_o = b_o; pa.res2 = res2;
    pa.otb2 = otb2; pa.out_orig = out_orig;
    prep_kernel<<<PREP_B6, 256, 0, stream>>>(pa);
  }

  // ---- 2: P1+P2 fused projections (stacked A: dinb|qin) ----
  {
    GArgs a{};
    a.A = dinb; a.Bt = BtKV; a.Bt2 = BtQG;
    a.M = 4608; a.N = 768; a.K = 384; a.Kld = 384;
    a.outb = Kh; a.outb2 = Vt; a.outb3 = Qb; a.outf = gateb; a.bias2 = b_g;
    gemm_bt<128, 64, 7><<<dim3(12, 36), 256, 0, stream>>>(a);
  }

  // ---- 3,4: attention + merge ----
  attn_kernel<<<dim3(8, 8, 8), 256, 0, stream>>>(
      Kh, Qb, Vt, (const unsigned char*)mbitsB, partO, partL);
  attn_merge<<<dim3(32, 8), 256, 0, stream>>>(partO, partL, gateb, attng);

  // ---- 5: P3 split-K=3 atomic into res2 (= resampled + b_o from prep) ----
  {
    GArgs a{};
    a.A = attng; a.Bt = OwT; a.M = 512; a.N = 384; a.K = 128; a.Kld = 384;
    a.outf = res2;
    gemm_bt<64, 64, 5><<<dim3(6, 8, 3), 256, 0, stream>>>(a);
  }
  // ---- 6: rt LN (tin) + out_res base (= res2 + rtb2) ----
  ln_rt<<<256, 256, 0, stream>>>(res2, rt_s, rt_o, rtb2, tin, out_res);
  // ---- 7: T1a ----
  {
    GArgs a{};
    a.A = tin; a.Bt = Rt1T; a.M = 512; a.N = 1536; a.K = 384; a.Kld = 384;
    a.bias = rtb1; a.outb = H1;
    gemm_bt<64, 64, 0><<<dim3(24, 8), 256, 0, stream>>>(a);
  }
  // ---- 8: T1b split-K=4 atomic into out_res ----
  {
    GArgs a{};
    a.A = H1; a.Bt = Rt2T; a.M = 512; a.N = 384; a.K = 384; a.Kld = 1536;
    a.outf = out_res;
    gemm_bt<64, 64, 5><<<dim3(6, 8, 4), 256, 0, stream>>>(a);
  }
  // ---- 9: T2a ----
  {
    GArgs a{};
    a.A = otin; a.Bt = Ot1T; a.M = 4096; a.N = 1536; a.K = 384; a.Kld = 384;
    a.bias = otb1; a.outb = H2;
    gemm_bt<128, 64, 0><<<dim3(24, 32), 256, 0, stream>>>(a);
  }
  // ---- 10: T2b split-K=2 atomic into out_orig (= original + otb2 from prep) ----
  {
    GArgs a{};
    a.A = H2; a.Bt = Ot2T; a.M = 4096; a.N = 384; a.K = 768; a.Kld = 1536;
    a.outf = out_orig;
    gemm_bt<128, 64, 5><<<dim3(6, 32, 2), 256, 0, stream>>>(a);
  }
}